// Round 1
// baseline (235.137 us; speedup 1.0000x reference)
//
#include <hip/hip_runtime.h>
#include <hip/hip_bf16.h>
#include <cstdint>
#include <cstddef>

typedef __bf16 bf16_t;
typedef __bf16 bf16x8 __attribute__((ext_vector_type(8)));
typedef __bf16 bf16x4 __attribute__((ext_vector_type(4)));
typedef float f32x4 __attribute__((ext_vector_type(4)));

#define DEVINL __device__ __forceinline__

DEVINL void gload_lds16(const void* g, void* l) {
  __builtin_amdgcn_global_load_lds(
      (__attribute__((address_space(1))) void*)(g),
      (__attribute__((address_space(3))) void*)(l), 16, 0, 0);
}

// ---------------------------------------------------------------------------
// cast fp32 -> bf16, vectorized (float4 in, 4x bf16 out)
// ---------------------------------------------------------------------------
__global__ __launch_bounds__(256) void cast_f32_bf16(
    const float* __restrict__ in, bf16_t* __restrict__ out, long n) {
  long i = ((long)blockIdx.x * 256 + threadIdx.x) * 4;
  if (i + 3 < n) {
    float4 v = *reinterpret_cast<const float4*>(in + i);
    bf16x4 o = { (bf16_t)v.x, (bf16_t)v.y, (bf16_t)v.z, (bf16_t)v.w };
    *reinterpret_cast<bf16x4*>(out + i) = o;
  }
}

// ---------------------------------------------------------------------------
// W [1024][3072] fp32 -> Wt [3072][1024] bf16 (LDS-tiled transpose)
// ---------------------------------------------------------------------------
__global__ __launch_bounds__(256) void transpose_W(
    const float* __restrict__ W, bf16_t* __restrict__ Wt) {
  __shared__ bf16_t tile[64][66];  // +2 pad: stride 132B = 33 words -> conflict-free
  const int c0 = blockIdx.x * 64, r0 = blockIdx.y * 64;
  const int tc = threadIdx.x & 63, tr = threadIdx.x >> 6;
#pragma unroll
  for (int k = 0; k < 16; ++k) {
    int rl = k * 4 + tr;
    tile[rl][tc] = (bf16_t)W[(size_t)(r0 + rl) * 3072 + c0 + tc];
  }
  __syncthreads();
#pragma unroll
  for (int k = 0; k < 16; ++k) {
    int cl = k * 4 + tr;
    Wt[(size_t)(c0 + cl) * 1024 + r0 + tc] = tile[tc][cl];
  }
}

// ---------------------------------------------------------------------------
// V slice of qkv [b][n][2048+h] bf16 -> Vt [b][h][n] bf16 (LDS-tiled transpose)
// ---------------------------------------------------------------------------
__global__ __launch_bounds__(256) void transpose_V(
    const bf16_t* __restrict__ qkv, bf16_t* __restrict__ Vt) {
  __shared__ bf16_t tile[64][66];
  const int b = blockIdx.z;
  const int h0 = blockIdx.x * 64, n0 = blockIdx.y * 64;
  const int tc = threadIdx.x & 63, tr = threadIdx.x >> 6;
#pragma unroll
  for (int k = 0; k < 16; ++k) {
    int nl = k * 4 + tr;
    tile[nl][tc] = qkv[((size_t)b * 2048 + n0 + nl) * 3072 + 2048 + h0 + tc];
  }
  __syncthreads();
#pragma unroll
  for (int k = 0; k < 16; ++k) {
    int hl = k * 4 + tr;
    Vt[((size_t)b * 1024 + h0 + hl) * 2048 + n0 + tc] = tile[tc][hl];
  }
}

// ---------------------------------------------------------------------------
// gemm_bt: C[M][N] = A[M][K] @ B[N][K]^T, bf16 in, fp32 accum.
// m97 structure: 128x128 tile, BK=32, 256 thr (2x2 waves, 64x64 each),
// global_load_lds width=16, mfma_f32_16x16x32_bf16.
// EPI 0: out bf16, v=(acc+bias[col])*(col<1024 ? 1/32 : 1)   (QKV proj)
// EPI 1: out fp32 plain
// ---------------------------------------------------------------------------
template <int EPI>
__global__ __launch_bounds__(256) void gemm_bt(
    const bf16_t* __restrict__ A, const bf16_t* __restrict__ B,
    void* __restrict__ C, const float* __restrict__ bias,
    int K, int lda, int ldb, int ldc,
    long sA, long sB, long sC) {
  __shared__ bf16_t As[128 * 32];
  __shared__ bf16_t Bs[128 * 32];

  const int tid = threadIdx.x;
  const int wave = tid >> 6, lane = tid & 63;
  const int wr = wave >> 1, wc = wave & 1;
  const int m0 = blockIdx.y * 128, n0 = blockIdx.x * 128;
  const int bz = blockIdx.z;

  A += (size_t)bz * sA;
  B += (size_t)bz * sB;

  const int srow = lane >> 2;        // 0..15 within 16-row chunk
  const int scol8 = (lane & 3) * 8;  // element offset in K

  f32x4 acc[4][4] = {};

  for (int kt = 0; kt < K; kt += 32) {
    // stage A,B tiles (each wave: 2 chunks of 16 rows x 32 cols)
#pragma unroll
    for (int c = 0; c < 2; ++c) {
      const int ch = wave * 2 + c;
      const int row = ch * 16 + srow;
      gload_lds16(A + (size_t)(m0 + row) * lda + kt + scol8, &As[ch * 512]);
      gload_lds16(B + (size_t)(n0 + row) * ldb + kt + scol8, &Bs[ch * 512]);
    }
    __syncthreads();

    bf16x8 af[4], bfr[4];
    const int rsel = lane & 15, ksel = (lane >> 4) * 8;
#pragma unroll
    for (int i = 0; i < 4; ++i)
      af[i] = *reinterpret_cast<const bf16x8*>(
          &As[(wr * 64 + i * 16 + rsel) * 32 + ksel]);
#pragma unroll
    for (int j = 0; j < 4; ++j)
      bfr[j] = *reinterpret_cast<const bf16x8*>(
          &Bs[(wc * 64 + j * 16 + rsel) * 32 + ksel]);
#pragma unroll
    for (int i = 0; i < 4; ++i)
#pragma unroll
      for (int j = 0; j < 4; ++j)
        acc[i][j] = __builtin_amdgcn_mfma_f32_16x16x32_bf16(
            af[i], bfr[j], acc[i][j], 0, 0, 0);
    __syncthreads();
  }

  // epilogue: C/D layout col=lane&15, row=(lane>>4)*4+reg (m89-verified)
  const int rbase = (lane >> 4) * 4;
  const int cselg = lane & 15;
#pragma unroll
  for (int i = 0; i < 4; ++i) {
#pragma unroll
    for (int j = 0; j < 4; ++j) {
#pragma unroll
      for (int r = 0; r < 4; ++r) {
        const int row = m0 + wr * 64 + i * 16 + rbase + r;
        const int col = n0 + wc * 64 + j * 16 + cselg;
        float v = acc[i][j][r];
        if constexpr (EPI == 0) {
          v = (v + bias[col]) * (col < 1024 ? 0.03125f : 1.0f);
          ((bf16_t*)C)[(size_t)bz * sC + (size_t)row * ldc + col] = (bf16_t)v;
        } else {
          ((float*)C)[(size_t)bz * sC + (size_t)row * ldc + col] = v;
        }
      }
    }
  }
}

// ---------------------------------------------------------------------------
// row softmax: S fp32 [8192 rows][2048] -> P bf16, one block per row
// ---------------------------------------------------------------------------
__global__ __launch_bounds__(256) void softmax_k(
    const float* __restrict__ S, bf16_t* __restrict__ P) {
  const long row = blockIdx.x;
  const float* s = S + row * 2048;
  const int tid = threadIdx.x;
  const int wave = tid >> 6, lane = tid & 63;

  float v[8];
  {
    const float4* s4 = reinterpret_cast<const float4*>(s + tid * 8);
    float4 a = s4[0], b = s4[1];
    v[0] = a.x; v[1] = a.y; v[2] = a.z; v[3] = a.w;
    v[4] = b.x; v[5] = b.y; v[6] = b.z; v[7] = b.w;
  }
  float m = v[0];
#pragma unroll
  for (int k = 1; k < 8; ++k) m = fmaxf(m, v[k]);
#pragma unroll
  for (int off = 32; off; off >>= 1) m = fmaxf(m, __shfl_xor(m, off));

  __shared__ float red[8];
  if (lane == 0) red[wave] = m;
  __syncthreads();
  m = fmaxf(fmaxf(red[0], red[1]), fmaxf(red[2], red[3]));

  float e[8], sum = 0.f;
#pragma unroll
  for (int k = 0; k < 8; ++k) { e[k] = __expf(v[k] - m); sum += e[k]; }
#pragma unroll
  for (int off = 32; off; off >>= 1) sum += __shfl_xor(sum, off);
  if (lane == 0) red[4 + wave] = sum;
  __syncthreads();
  sum = red[4] + red[5] + red[6] + red[7];
  const float inv = 1.0f / sum;

  bf16x8 o;
#pragma unroll
  for (int k = 0; k < 8; ++k) o[k] = (bf16_t)(e[k] * inv);
  *reinterpret_cast<bf16x8*>(P + row * 2048 + tid * 8) = o;
}

// ---------------------------------------------------------------------------
// launch
// ---------------------------------------------------------------------------
extern "C" void kernel_launch(void* const* d_in, const int* in_sizes, int n_in,
                              void* d_out, int out_size, void* d_ws,
                              size_t ws_size, hipStream_t stream) {
  const float* x = (const float*)d_in[0];  // [4,2048,1024]
  const float* W = (const float*)d_in[1];  // [1024,3072]
  const float* b = (const float*)d_in[2];  // [3072]
  float* out = (float*)d_out;              // [4,2048,1024] fp32

  // workspace carve (~191 MB)
  char* w = (char*)d_ws;
  bf16_t* xb = (bf16_t*)w;   w += (size_t)8192 * 1024 * 2;      // 16.8 MB
  bf16_t* Wt = (bf16_t*)w;   w += (size_t)3072 * 1024 * 2;      //  6.3 MB
  bf16_t* qkv = (bf16_t*)w;  w += (size_t)8192 * 3072 * 2;      // 50.3 MB
  bf16_t* Vt = (bf16_t*)w;   w += (size_t)4 * 1024 * 2048 * 2;  // 16.8 MB
  float* S = (float*)w;      w += (size_t)4 * 2048 * 2048 * 4;  // 67.1 MB
  bf16_t* P = (bf16_t*)w;    w += (size_t)4 * 2048 * 2048 * 2;  // 33.6 MB

  // 1. x -> bf16
  cast_f32_bf16<<<8192, 256, 0, stream>>>(x, xb, (long)8192 * 1024);
  // 2. W -> Wt (bf16, transposed)
  transpose_W<<<dim3(48, 16), 256, 0, stream>>>(W, Wt);
  // 3. qkv = x @ W + b  (Q scaled by 1/32), bf16 out
  gemm_bt<0><<<dim3(24, 64, 1), 256, 0, stream>>>(
      xb, Wt, qkv, b, 1024, 1024, 1024, 3072, 0, 0, 0);
  // 4. Vt[b][h][n]
  transpose_V<<<dim3(16, 32, 4), 256, 0, stream>>>(qkv, Vt);
  // 5. S = Qs @ K^T  (fp32 out), per batch
  gemm_bt<1><<<dim3(16, 16, 4), 256, 0, stream>>>(
      qkv, qkv + 1024, S, nullptr, 1024, 3072, 3072, 2048,
      (long)2048 * 3072, (long)2048 * 3072, (long)2048 * 2048);
  // 6. P = softmax(S) rows, bf16 out
  softmax_k<<<8192, 256, 0, stream>>>(S, P);
  // 7. out = P @ Vt^T (fp32 out), per batch
  gemm_bt<1><<<dim3(8, 16, 4), 256, 0, stream>>>(
      P, Vt, out, nullptr, 2048, 2048, 2048, 1024,
      (long)2048 * 2048, (long)1024 * 2048, (long)2048 * 1024);
}

// Round 2
// 193.019 us; speedup vs baseline: 1.2182x; 1.2182x over previous
//
#include <hip/hip_runtime.h>
#include <hip/hip_bf16.h>
#include <cstdint>
#include <cstddef>

typedef __bf16 bf16_t;
typedef __bf16 bf16x8 __attribute__((ext_vector_type(8)));
typedef __bf16 bf16x4 __attribute__((ext_vector_type(4)));
typedef float f32x4 __attribute__((ext_vector_type(4)));

#define DEVINL __device__ __forceinline__

DEVINL void gload_lds16(const bf16_t* g, bf16_t* l) {
  __builtin_amdgcn_global_load_lds(
      (__attribute__((address_space(1))) void*)(g),
      (__attribute__((address_space(3))) void*)(l), 16, 0, 0);
}

// ---------------------------------------------------------------------------
// cast fp32 -> bf16
// ---------------------------------------------------------------------------
__global__ __launch_bounds__(256) void cast_f32_bf16(
    const float* __restrict__ in, bf16_t* __restrict__ out, long n) {
  long i = ((long)blockIdx.x * 256 + threadIdx.x) * 4;
  if (i + 3 < n) {
    float4 v = *reinterpret_cast<const float4*>(in + i);
    bf16x4 o = { (bf16_t)v.x, (bf16_t)v.y, (bf16_t)v.z, (bf16_t)v.w };
    *reinterpret_cast<bf16x4*>(out + i) = o;
  }
}

// ---------------------------------------------------------------------------
// W [1024][3072] fp32 -> Wt [3072][1024] bf16
// ---------------------------------------------------------------------------
__global__ __launch_bounds__(256) void transpose_W(
    const float* __restrict__ W, bf16_t* __restrict__ Wt) {
  __shared__ bf16_t tile[64][66];
  const int c0 = blockIdx.x * 64, r0 = blockIdx.y * 64;
  const int tc = threadIdx.x & 63, tr = threadIdx.x >> 6;
#pragma unroll
  for (int k = 0; k < 16; ++k) {
    int rl = k * 4 + tr;
    tile[rl][tc] = (bf16_t)W[(size_t)(r0 + rl) * 3072 + c0 + tc];
  }
  __syncthreads();
#pragma unroll
  for (int k = 0; k < 16; ++k) {
    int cl = k * 4 + tr;
    Wt[(size_t)(c0 + cl) * 1024 + r0 + tc] = tile[tc][cl];
  }
}

// ---------------------------------------------------------------------------
// V slice of qkv -> Vt [b][h][n] bf16
// ---------------------------------------------------------------------------
__global__ __launch_bounds__(256) void transpose_V(
    const bf16_t* __restrict__ qkv, bf16_t* __restrict__ Vt) {
  __shared__ bf16_t tile[64][66];
  const int b = blockIdx.z;
  const int h0 = blockIdx.x * 64, n0 = blockIdx.y * 64;
  const int tc = threadIdx.x & 63, tr = threadIdx.x >> 6;
#pragma unroll
  for (int k = 0; k < 16; ++k) {
    int nl = k * 4 + tr;
    tile[nl][tc] = qkv[((size_t)b * 2048 + n0 + nl) * 3072 + 2048 + h0 + tc];
  }
  __syncthreads();
#pragma unroll
  for (int k = 0; k < 16; ++k) {
    int hl = k * 4 + tr;
    Vt[((size_t)b * 1024 + h0 + hl) * 2048 + n0 + tc] = tile[tc][hl];
  }
}

// ---------------------------------------------------------------------------
// gemm256: C[M][BNxNtiles] = A[M][K] @ B[N][K]^T, 256xBN tile, BK=64.
// 512 threads (8 waves). 4 phases per K-tile: (hi, ks). k-half LDS subtiles
// [rows][32] (stride 64B -> conflict-free ds_read_b128). Counted vmcnt
// (never 0 in main loop), setprio around MFMA, 2 barriers/phase.
// EPI 0: bf16 out, (acc+bias[col])*(col<1024 ? 1/32 : 1)
// EPI 1: fp32 out plain
// ---------------------------------------------------------------------------
template <int BN, int EPI>
__global__ __launch_bounds__(512, 2) void gemm256(
    const bf16_t* __restrict__ A, const bf16_t* __restrict__ B,
    void* __restrict__ C, const float* __restrict__ bias,
    int K, int lda, int ldb, int ldc,
    long sA, long sB, long sC) {
  constexpr int WN = BN / 64;        // waves along N (4 or 2)
  constexpr int WM = 8 / WN;         // waves along M (2 or 4)
  constexpr int MR = (256 / WM) / 16;  // row frags per wave (8 or 4)
  constexpr int IB = BN / 128;       // B gload instr/thread/half (2 or 1)
  constexpr int VW = 2 * (2 + IB);   // steady-state vmcnt
  constexpr int HTE = (256 + BN) * 32;  // elements per (buf, ks)

  __shared__ bf16_t lds[2][2][HTE];  // [buf][k-half][A 256x32 | B BNx32]

  // XCD-aware swizzle (nwg % 8 == 0 for all our grids)
  const int gx = gridDim.x, gy = gridDim.y;
  const int nwg = gx * gy * gridDim.z;
  const int flat = blockIdx.x + gx * (blockIdx.y + gy * blockIdx.z);
  const int swz = (flat & 7) * (nwg >> 3) + (flat >> 3);
  const int bx = swz % gx;
  const int rem = swz / gx;
  const int by = rem % gy, bz = rem / gy;

  const int m0 = by * 256, n0 = bx * BN;
  A += (size_t)bz * sA;
  B += (size_t)bz * sB;

  const int tid = threadIdx.x;
  const int w = tid >> 6, lane = tid & 63;
  const int wr = w / WN, wc = w % WN;

  // staging source: lane -> (row = lane>>2, col chunk = (lane&3)*8)
  const int srow = lane >> 2, scol = (lane & 3) * 8;
  const bf16_t* gA = A + (size_t)(m0 + w * 32 + srow) * lda + scol;
  const bf16_t* gB = B + (size_t)(n0 + w * (IB == 2 ? 32 : 16) + srow) * ldb + scol;

  auto stageA = [&](int t, int ks) {
    const bf16_t* g = gA + (size_t)t * 64 + ks * 32;
    bf16_t* l = &lds[t & 1][ks][(w * 32) * 32];
    gload_lds16(g, l);
    gload_lds16(g + (size_t)16 * lda, l + 16 * 32);
  };
  auto stageB = [&](int t, int ks) {
    const bf16_t* g = gB + (size_t)t * 64 + ks * 32;
    if constexpr (IB == 2) {
      bf16_t* l = &lds[t & 1][ks][256 * 32 + (w * 32) * 32];
      gload_lds16(g, l);
      gload_lds16(g + (size_t)16 * ldb, l + 16 * 32);
    } else {
      bf16_t* l = &lds[t & 1][ks][256 * 32 + (w * 16) * 32];
      gload_lds16(g, l);
    }
  };

  const int rsel = lane & 15, kg = lane >> 4;
  f32x4 acc[MR][4] = {};
  bf16x8 af[MR / 2], bfr[4];

  auto ldA = [&](int b, int ks, int fi) -> bf16x8 {
    return *reinterpret_cast<const bf16x8*>(
        &lds[b][ks][(wr * (MR * 16) + fi * 16 + rsel) * 32 + kg * 8]);
  };
  auto ldB = [&](int b, int ks, int fj) -> bf16x8 {
    return *reinterpret_cast<const bf16x8*>(
        &lds[b][ks][256 * 32 + (wc * 64 + fj * 16 + rsel) * 32 + kg * 8]);
  };

#define PHASE(b, hi, ks, STG, TAILASM)                                        \
  {                                                                           \
    if ((hi) == 0) {                                                          \
      _Pragma("unroll") for (int j = 0; j < 4; ++j) bfr[j] = ldB(b, ks, j);   \
    }                                                                         \
    _Pragma("unroll") for (int i = 0; i < MR / 2; ++i)                        \
        af[i] = ldA(b, ks, (hi) * (MR / 2) + i);                              \
    STG;                                                                      \
    __builtin_amdgcn_s_barrier();                                             \
    asm volatile("s_waitcnt lgkmcnt(0)" ::: "memory");                        \
    __builtin_amdgcn_s_setprio(1);                                            \
    _Pragma("unroll") for (int i = 0; i < MR / 2; ++i)                        \
        _Pragma("unroll") for (int j = 0; j < 4; ++j)                         \
            acc[(hi) * (MR / 2) + i][j] =                                     \
        __builtin_amdgcn_mfma_f32_16x16x32_bf16(                              \
            af[i], bfr[j], acc[(hi) * (MR / 2) + i][j], 0, 0, 0);             \
    __builtin_amdgcn_s_setprio(0);                                            \
    TAILASM;                                                                  \
    __builtin_amdgcn_s_barrier();                                             \
  }

#define VMW_MAIN asm volatile("s_waitcnt vmcnt(%0)" ::"n"(VW) : "memory")
#define VMW_PEEL asm volatile("s_waitcnt vmcnt(%0)" ::"n"(2 + IB) : "memory")
#define VMW_ZERO asm volatile("s_waitcnt vmcnt(0)" ::: "memory")

  const int NT = K >> 6;

  // prologue: stage k0(0), k1(0), k0(1)
  stageA(0, 0); stageB(0, 0);
  stageA(0, 1); stageB(0, 1);
  stageA(1, 0); stageB(1, 0);
  VMW_MAIN;
  __builtin_amdgcn_s_barrier();

  for (int t = 0; t < NT - 1; ++t) {
    const int b = t & 1;
    PHASE(b, 0, 0, { stageA(t + 1, 1); }, );
    PHASE(b, 1, 0, { stageB(t + 1, 1); }, VMW_MAIN);
    PHASE(b, 0, 1, { if (t < NT - 2) stageA(t + 2, 0); }, );
    PHASE(b, 1, 1, { if (t < NT - 2) stageB(t + 2, 0); },
          if (t == NT - 2) { VMW_PEEL; } else { VMW_MAIN; });
  }
  // peeled last K-tile (drain)
  {
    const int b = (NT - 1) & 1;
    PHASE(b, 0, 0, , );
    PHASE(b, 1, 0, , VMW_ZERO);
    PHASE(b, 0, 1, , );
    PHASE(b, 1, 1, , );
  }
#undef PHASE
#undef VMW_MAIN
#undef VMW_PEEL
#undef VMW_ZERO

  // epilogue: C/D layout col=lane&15, row=(lane>>4)*4+reg (m89-verified)
  const int rb = (lane >> 4) * 4, cs = lane & 15;
#pragma unroll
  for (int i = 0; i < MR; ++i) {
#pragma unroll
    for (int j = 0; j < 4; ++j) {
#pragma unroll
      for (int r = 0; r < 4; ++r) {
        const int row = m0 + wr * (MR * 16) + i * 16 + rb + r;
        const int col = n0 + wc * 64 + j * 16 + cs;
        float v = acc[i][j][r];
        if constexpr (EPI == 0) {
          v = (v + bias[col]) * (col < 1024 ? 0.03125f : 1.0f);
          ((bf16_t*)C)[(size_t)bz * sC + (size_t)row * ldc + col] = (bf16_t)v;
        } else {
          ((float*)C)[(size_t)bz * sC + (size_t)row * ldc + col] = v;
        }
      }
    }
  }
}

// ---------------------------------------------------------------------------
// row softmax: S fp32 [8192 rows][2048] -> P bf16
// ---------------------------------------------------------------------------
__global__ __launch_bounds__(256) void softmax_k(
    const float* __restrict__ S, bf16_t* __restrict__ P) {
  const long row = blockIdx.x;
  const float* s = S + row * 2048;
  const int tid = threadIdx.x;
  const int wave = tid >> 6, lane = tid & 63;

  float v[8];
  {
    const float4* s4 = reinterpret_cast<const float4*>(s + tid * 8);
    float4 a = s4[0], b = s4[1];
    v[0] = a.x; v[1] = a.y; v[2] = a.z; v[3] = a.w;
    v[4] = b.x; v[5] = b.y; v[6] = b.z; v[7] = b.w;
  }
  float m = v[0];
#pragma unroll
  for (int k = 1; k < 8; ++k) m = fmaxf(m, v[k]);
#pragma unroll
  for (int off = 32; off; off >>= 1) m = fmaxf(m, __shfl_xor(m, off));

  __shared__ float red[8];
  if (lane == 0) red[wave] = m;
  __syncthreads();
  m = fmaxf(fmaxf(red[0], red[1]), fmaxf(red[2], red[3]));

  float e[8], sum = 0.f;
#pragma unroll
  for (int k = 0; k < 8; ++k) { e[k] = __expf(v[k] - m); sum += e[k]; }
#pragma unroll
  for (int off = 32; off; off >>= 1) sum += __shfl_xor(sum, off);
  if (lane == 0) red[4 + wave] = sum;
  __syncthreads();
  sum = red[4] + red[5] + red[6] + red[7];
  const float inv = 1.0f / sum;

  bf16x8 o;
#pragma unroll
  for (int k = 0; k < 8; ++k) o[k] = (bf16_t)(e[k] * inv);
  *reinterpret_cast<bf16x8*>(P + row * 2048 + tid * 8) = o;
}

// ---------------------------------------------------------------------------
// launch
// ---------------------------------------------------------------------------
extern "C" void kernel_launch(void* const* d_in, const int* in_sizes, int n_in,
                              void* d_out, int out_size, void* d_ws,
                              size_t ws_size, hipStream_t stream) {
  const float* x = (const float*)d_in[0];  // [4,2048,1024]
  const float* W = (const float*)d_in[1];  // [1024,3072]
  const float* b = (const float*)d_in[2];  // [3072]
  float* out = (float*)d_out;              // [4,2048,1024] fp32

  char* w = (char*)d_ws;
  bf16_t* xb = (bf16_t*)w;   w += (size_t)8192 * 1024 * 2;
  bf16_t* Wt = (bf16_t*)w;   w += (size_t)3072 * 1024 * 2;
  bf16_t* qkv = (bf16_t*)w;  w += (size_t)8192 * 3072 * 2;
  bf16_t* Vt = (bf16_t*)w;   w += (size_t)4 * 1024 * 2048 * 2;
  float* S = (float*)w;      w += (size_t)4 * 2048 * 2048 * 4;
  bf16_t* P = (bf16_t*)w;    w += (size_t)4 * 2048 * 2048 * 2;

  cast_f32_bf16<<<8192, 256, 0, stream>>>(x, xb, (long)8192 * 1024);
  transpose_W<<<dim3(48, 16), 256, 0, stream>>>(W, Wt);

  // qkv = x @ W + b (Q scaled by 1/32), bf16 out. grid 12x32 = 384 wgs
  gemm256<256, 0><<<dim3(12, 32, 1), 512, 0, stream>>>(
      xb, Wt, qkv, b, 1024, 1024, 1024, 3072, 0, 0, 0);

  transpose_V<<<dim3(16, 32, 4), 256, 0, stream>>>(qkv, Vt);

  // S = Qs @ K^T, fp32 out. grid 8x8x4 = 256 wgs
  gemm256<256, 1><<<dim3(8, 8, 4), 512, 0, stream>>>(
      qkv, qkv + 1024, S, nullptr, 1024, 3072, 3072, 2048,
      (long)2048 * 3072, (long)2048 * 3072, (long)2048 * 2048);

  softmax_k<<<8192, 256, 0, stream>>>(S, P);

  // out = P @ Vt^T, fp32 out, 256x128 tile variant. grid 8x8x4 = 256 wgs
  gemm256<128, 1><<<dim3(8, 8, 4), 512, 0, stream>>>(
      P, Vt, out, nullptr, 2048, 2048, 2048, 1024,
      (long)2048 * 2048, (long)1024 * 2048, (long)2048 * 1024);
}

// Round 3
// 186.754 us; speedup vs baseline: 1.2591x; 1.0336x over previous
//
#include <hip/hip_runtime.h>
#include <hip/hip_bf16.h>
#include <cstdint>
#include <cstddef>

typedef __bf16 bf16_t;
typedef __bf16 bf16x8 __attribute__((ext_vector_type(8)));
typedef __bf16 bf16x4 __attribute__((ext_vector_type(4)));
typedef float f32x4 __attribute__((ext_vector_type(4)));

#define DEVINL __device__ __forceinline__

DEVINL void gload_lds16(const bf16_t* g, bf16_t* l) {
  __builtin_amdgcn_global_load_lds(
      (__attribute__((address_space(1))) void*)(g),
      (__attribute__((address_space(3))) void*)(l), 16, 0, 0);
}

// ---------------------------------------------------------------------------
// cast fp32 -> bf16
// ---------------------------------------------------------------------------
__global__ __launch_bounds__(256) void cast_f32_bf16(
    const float* __restrict__ in, bf16_t* __restrict__ out, long n) {
  long i = ((long)blockIdx.x * 256 + threadIdx.x) * 4;
  if (i + 3 < n) {
    float4 v = *reinterpret_cast<const float4*>(in + i);
    bf16x4 o = { (bf16_t)v.x, (bf16_t)v.y, (bf16_t)v.z, (bf16_t)v.w };
    *reinterpret_cast<bf16x4*>(out + i) = o;
  }
}

// ---------------------------------------------------------------------------
// W [1024][3072] fp32 -> Wt [3072][1024] bf16
// ---------------------------------------------------------------------------
__global__ __launch_bounds__(256) void transpose_W(
    const float* __restrict__ W, bf16_t* __restrict__ Wt) {
  __shared__ bf16_t tile[64][66];
  const int c0 = blockIdx.x * 64, r0 = blockIdx.y * 64;
  const int tc = threadIdx.x & 63, tr = threadIdx.x >> 6;
#pragma unroll
  for (int k = 0; k < 16; ++k) {
    int rl = k * 4 + tr;
    tile[rl][tc] = (bf16_t)W[(size_t)(r0 + rl) * 3072 + c0 + tc];
  }
  __syncthreads();
#pragma unroll
  for (int k = 0; k < 16; ++k) {
    int cl = k * 4 + tr;
    Wt[(size_t)(c0 + cl) * 1024 + r0 + tc] = tile[tc][cl];
  }
}

// ---------------------------------------------------------------------------
// V slice of qkv -> Vt [b][h][n] bf16
// ---------------------------------------------------------------------------
__global__ __launch_bounds__(256) void transpose_V(
    const bf16_t* __restrict__ qkv, bf16_t* __restrict__ Vt) {
  __shared__ bf16_t tile[64][66];
  const int b = blockIdx.z;
  const int h0 = blockIdx.x * 64, n0 = blockIdx.y * 64;
  const int tc = threadIdx.x & 63, tr = threadIdx.x >> 6;
#pragma unroll
  for (int k = 0; k < 16; ++k) {
    int nl = k * 4 + tr;
    tile[nl][tc] = qkv[((size_t)b * 2048 + n0 + nl) * 3072 + 2048 + h0 + tc];
  }
  __syncthreads();
#pragma unroll
  for (int k = 0; k < 16; ++k) {
    int hl = k * 4 + tr;
    Vt[((size_t)b * 1024 + h0 + hl) * 2048 + n0 + tc] = tile[tc][hl];
  }
}

// ---------------------------------------------------------------------------
// gemm256: C[M][N] = A[M][K] @ B[N][K]^T, 256xBN tile, BK=64, 512 threads.
// 4 phases per K-tile. k-half LDS subtiles [rows][32] with T2 slot-swizzle:
// 16B slot s of row r holds global k-chunk s ^ ((r>>1)&3). Pre-swizzled
// global source (gload_lds dest stays linear, rule #21) + XOR'd ds_read.
// -> each 16-lane b128 read group covers all 8 bank-quads at 2 dw/bank floor.
// Counted vmcnt (never 0 in main loop), setprio around MFMA.
// EPI 0: bf16 out, (acc+bias[col])*(col<1024 ? 1/32 : 1);  EPI 1: fp32 out.
// ---------------------------------------------------------------------------
template <int BN, int EPI>
__global__ __launch_bounds__(512, 2) void gemm256(
    const bf16_t* __restrict__ A, const bf16_t* __restrict__ B,
    void* __restrict__ C, const float* __restrict__ bias,
    int K, int lda, int ldb, int ldc,
    long sA, long sB, long sC) {
  constexpr int WN = BN / 64;          // waves along N (4 or 2)
  constexpr int WM = 8 / WN;           // waves along M (2 or 4)
  constexpr int MR = (256 / WM) / 16;  // row frags per wave (8 or 4)
  constexpr int IB = BN / 128;         // B gload instr/thread/half (2 or 1)
  constexpr int VW = 2 * (2 + IB);     // steady-state vmcnt
  constexpr int HTE = (256 + BN) * 32; // elements per (buf, ks)

  __shared__ bf16_t lds[2][2][HTE];  // [buf][k-half][A 256x32 | B BNx32]

  // XCD-aware swizzle (nwg % 8 == 0 for all our grids)
  const int gx = gridDim.x, gy = gridDim.y;
  const int nwg = gx * gy * gridDim.z;
  const int flat = blockIdx.x + gx * (blockIdx.y + gy * blockIdx.z);
  const int swz = (flat & 7) * (nwg >> 3) + (flat >> 3);
  const int bx = swz % gx;
  const int rem = swz / gx;
  const int by = rem % gy, bz = rem / gy;

  const int m0 = by * 256, n0 = bx * BN;
  A += (size_t)bz * sA;
  B += (size_t)bz * sB;

  const int tid = threadIdx.x;
  const int w = tid >> 6, lane = tid & 63;
  const int wr = w / WN, wc = w % WN;

  // staging source: lane -> row = lane>>2, k-chunk = (lane&3)^((lane>>3)&3)
  // (T2 pre-swizzled source; valid for any 16-row-aligned stripe base)
  const int srow = lane >> 2;
  const int schunk = ((lane & 3) ^ ((lane >> 3) & 3)) * 8;
  const bf16_t* gA = A + (size_t)(m0 + w * 32 + srow) * lda + schunk;
  const bf16_t* gB = B + (size_t)(n0 + w * (IB == 2 ? 32 : 16) + srow) * ldb + schunk;

  auto stageA = [&](int t, int ks) {
    const bf16_t* g = gA + (size_t)t * 64 + ks * 32;
    bf16_t* l = &lds[t & 1][ks][(w * 32) * 32];
    gload_lds16(g, l);
    gload_lds16(g + (size_t)16 * lda, l + 16 * 32);
  };
  auto stageB = [&](int t, int ks) {
    const bf16_t* g = gB + (size_t)t * 64 + ks * 32;
    if constexpr (IB == 2) {
      bf16_t* l = &lds[t & 1][ks][256 * 32 + (w * 32) * 32];
      gload_lds16(g, l);
      gload_lds16(g + (size_t)16 * ldb, l + 16 * 32);
    } else {
      bf16_t* l = &lds[t & 1][ks][256 * 32 + (w * 16) * 32];
      gload_lds16(g, l);
    }
  };

  const int rsel = lane & 15, kg = lane >> 4;
  const int kswz = (kg ^ ((rsel >> 1) & 3)) * 8;  // T2 read-side XOR
  f32x4 acc[MR][4] = {};
  bf16x8 af[MR / 2], bfr[4];

  auto ldA = [&](int b, int ks, int fi) -> bf16x8 {
    return *reinterpret_cast<const bf16x8*>(
        &lds[b][ks][(wr * (MR * 16) + fi * 16 + rsel) * 32 + kswz]);
  };
  auto ldB = [&](int b, int ks, int fj) -> bf16x8 {
    return *reinterpret_cast<const bf16x8*>(
        &lds[b][ks][256 * 32 + (wc * 64 + fj * 16 + rsel) * 32 + kswz]);
  };

#define PHASE(b, hi, ks, STG, TAILASM)                                        \
  {                                                                           \
    if ((hi) == 0) {                                                          \
      _Pragma("unroll") for (int j = 0; j < 4; ++j) bfr[j] = ldB(b, ks, j);   \
    }                                                                         \
    _Pragma("unroll") for (int i = 0; i < MR / 2; ++i)                        \
        af[i] = ldA(b, ks, (hi) * (MR / 2) + i);                              \
    STG;                                                                      \
    __builtin_amdgcn_s_barrier();                                             \
    asm volatile("s_waitcnt lgkmcnt(0)" ::: "memory");                        \
    __builtin_amdgcn_s_setprio(1);                                            \
    _Pragma("unroll") for (int i = 0; i < MR / 2; ++i)                        \
        _Pragma("unroll") for (int j = 0; j < 4; ++j)                         \
            acc[(hi) * (MR / 2) + i][j] =                                     \
        __builtin_amdgcn_mfma_f32_16x16x32_bf16(                              \
            af[i], bfr[j], acc[(hi) * (MR / 2) + i][j], 0, 0, 0);             \
    __builtin_amdgcn_s_setprio(0);                                            \
    TAILASM;                                                                  \
    __builtin_amdgcn_s_barrier();                                             \
  }

#define VMW_MAIN asm volatile("s_waitcnt vmcnt(%0)" ::"n"(VW) : "memory")
#define VMW_PEEL asm volatile("s_waitcnt vmcnt(%0)" ::"n"(2 + IB) : "memory")
#define VMW_ZERO asm volatile("s_waitcnt vmcnt(0)" ::: "memory")

  const int NT = K >> 6;

  // prologue: stage k0(0), k1(0), k0(1)
  stageA(0, 0); stageB(0, 0);
  stageA(0, 1); stageB(0, 1);
  stageA(1, 0); stageB(1, 0);
  VMW_MAIN;
  __builtin_amdgcn_s_barrier();

  for (int t = 0; t < NT - 1; ++t) {
    const int b = t & 1;
    PHASE(b, 0, 0, { stageA(t + 1, 1); }, );
    PHASE(b, 1, 0, { stageB(t + 1, 1); }, VMW_MAIN);
    PHASE(b, 0, 1, { if (t < NT - 2) stageA(t + 2, 0); }, );
    PHASE(b, 1, 1, { if (t < NT - 2) stageB(t + 2, 0); },
          if (t == NT - 2) { VMW_PEEL; } else { VMW_MAIN; });
  }
  // peeled last K-tile (drain)
  {
    const int b = (NT - 1) & 1;
    PHASE(b, 0, 0, , );
    PHASE(b, 1, 0, , VMW_ZERO);
    PHASE(b, 0, 1, , );
    PHASE(b, 1, 1, , );
  }
#undef PHASE
#undef VMW_MAIN
#undef VMW_PEEL
#undef VMW_ZERO

  // epilogue: C/D layout col=lane&15, row=(lane>>4)*4+reg (m89-verified)
  const int rb = (lane >> 4) * 4, cs = lane & 15;
#pragma unroll
  for (int i = 0; i < MR; ++i) {
#pragma unroll
    for (int j = 0; j < 4; ++j) {
#pragma unroll
      for (int r = 0; r < 4; ++r) {
        const int row = m0 + wr * (MR * 16) + i * 16 + rb + r;
        const int col = n0 + wc * 64 + j * 16 + cs;
        float v = acc[i][j][r];
        if constexpr (EPI == 0) {
          v = (v + bias[col]) * (col < 1024 ? 0.03125f : 1.0f);
          ((bf16_t*)C)[(size_t)bz * sC + (size_t)row * ldc + col] = (bf16_t)v;
        } else {
          ((float*)C)[(size_t)bz * sC + (size_t)row * ldc + col] = v;
        }
      }
    }
  }
}

// ---------------------------------------------------------------------------
// row softmax: S fp32 [8192 rows][2048] -> P bf16
// ---------------------------------------------------------------------------
__global__ __launch_bounds__(256) void softmax_k(
    const float* __restrict__ S, bf16_t* __restrict__ P) {
  const long row = blockIdx.x;
  const float* s = S + row * 2048;
  const int tid = threadIdx.x;
  const int wave = tid >> 6, lane = tid & 63;

  float v[8];
  {
    const float4* s4 = reinterpret_cast<const float4*>(s + tid * 8);
    float4 a = s4[0], b = s4[1];
    v[0] = a.x; v[1] = a.y; v[2] = a.z; v[3] = a.w;
    v[4] = b.x; v[5] = b.y; v[6] = b.z; v[7] = b.w;
  }
  float m = v[0];
#pragma unroll
  for (int k = 1; k < 8; ++k) m = fmaxf(m, v[k]);
#pragma unroll
  for (int off = 32; off; off >>= 1) m = fmaxf(m, __shfl_xor(m, off));

  __shared__ float red[8];
  if (lane == 0) red[wave] = m;
  __syncthreads();
  m = fmaxf(fmaxf(red[0], red[1]), fmaxf(red[2], red[3]));

  float e[8], sum = 0.f;
#pragma unroll
  for (int k = 0; k < 8; ++k) { e[k] = __expf(v[k] - m); sum += e[k]; }
#pragma unroll
  for (int off = 32; off; off >>= 1) sum += __shfl_xor(sum, off);
  if (lane == 0) red[4 + wave] = sum;
  __syncthreads();
  sum = red[4] + red[5] + red[6] + red[7];
  const float inv = 1.0f / sum;

  bf16x8 o;
#pragma unroll
  for (int k = 0; k < 8; ++k) o[k] = (bf16_t)(e[k] * inv);
  *reinterpret_cast<bf16x8*>(P + row * 2048 + tid * 8) = o;
}

// ---------------------------------------------------------------------------
// launch
// ---------------------------------------------------------------------------
extern "C" void kernel_launch(void* const* d_in, const int* in_sizes, int n_in,
                              void* d_out, int out_size, void* d_ws,
                              size_t ws_size, hipStream_t stream) {
  const float* x = (const float*)d_in[0];  // [4,2048,1024]
  const float* W = (const float*)d_in[1];  // [1024,3072]
  const float* b = (const float*)d_in[2];  // [3072]
  float* out = (float*)d_out;              // [4,2048,1024] fp32

  char* w = (char*)d_ws;
  bf16_t* xb = (bf16_t*)w;   w += (size_t)8192 * 1024 * 2;
  bf16_t* Wt = (bf16_t*)w;   w += (size_t)3072 * 1024 * 2;
  bf16_t* qkv = (bf16_t*)w;  w += (size_t)8192 * 3072 * 2;
  bf16_t* Vt = (bf16_t*)w;   w += (size_t)4 * 1024 * 2048 * 2;
  float* S = (float*)w;      w += (size_t)4 * 2048 * 2048 * 4;
  bf16_t* P = (bf16_t*)w;    w += (size_t)4 * 2048 * 2048 * 2;

  cast_f32_bf16<<<8192, 256, 0, stream>>>(x, xb, (long)8192 * 1024);
  transpose_W<<<dim3(48, 16), 256, 0, stream>>>(W, Wt);

  // qkv = x @ W + b (Q scaled by 1/32), bf16 out. grid 12x32 = 384 wgs
  gemm256<256, 0><<<dim3(12, 32, 1), 512, 0, stream>>>(
      xb, Wt, qkv, b, 1024, 1024, 1024, 3072, 0, 0, 0);

  transpose_V<<<dim3(16, 32, 4), 256, 0, stream>>>(qkv, Vt);

  // S = Qs @ K^T, fp32 out. grid 8x8x4 = 256 wgs
  gemm256<256, 1><<<dim3(8, 8, 4), 512, 0, stream>>>(
      qkv, qkv + 1024, S, nullptr, 1024, 3072, 3072, 2048,
      (long)2048 * 3072, (long)2048 * 3072, (long)2048 * 2048);

  softmax_k<<<8192, 256, 0, stream>>>(S, P);

  // out = P @ Vt^T, fp32 out, 256x128 tile variant. grid 8x8x4 = 256 wgs
  gemm256<128, 1><<<dim3(8, 8, 4), 512, 0, stream>>>(
      P, Vt, out, nullptr, 2048, 2048, 2048, 1024,
      (long)2048 * 2048, (long)1024 * 2048, (long)2048 * 1024);
}